// Round 1
// baseline (177.726 us; speedup 1.0000x reference)
//
#include <hip/hip_runtime.h>

#define NPTS 512
#define BLOCK 256

// One block per batch: stage (src,tgt,w) to LDS with float4 loads, reduce 16
// weighted moments (W, m_s, m_t, M=sum w*s*t^T), then thread 0 does the 3x3
// Procrustes solve in double precision.
//
// Algebra: with T = sum(w)+eps, normalized weights wn = w/T:
//   src_c = m_s/T, tgt_c = m_t/T
//   H = M/T - (2 - W/T) * src_c * tgt_c^T     (exact expansion of the
//   centered covariance sum; no second pass over points needed)
// SVD-free rotation: eigendecomp A = H^T H = V diag(lam) V^T (Jacobi),
// v3 := v1 x v2, u_i = H v_i normalized (Gram-Schmidt), u3 := u1 x u2.
// Then R = V U^T -- the cross products make det(U)=det(V)=+1, which is
// exactly the reference's diag(1,1,sign(det(V U^T))) reflection fix.
__global__ __launch_bounds__(BLOCK) void wproc_kernel(
    const float* __restrict__ src,
    const float* __restrict__ tgt,
    const float* __restrict__ wts,
    float* __restrict__ out,
    int B)
{
    const int b = blockIdx.x;
    const int t = threadIdx.x;

    __shared__ float s_s[NPTS * 3];
    __shared__ float s_t[NPTS * 3];
    __shared__ float s_w[NPTS];

    {
        const float4* sb4 = (const float4*)(src + (size_t)b * (NPTS * 3));
        const float4* tb4 = (const float4*)(tgt + (size_t)b * (NPTS * 3));
        const float4* wb4 = (const float4*)(wts + (size_t)b * NPTS);
        float4* ss4 = (float4*)s_s;
        float4* st4 = (float4*)s_t;
        float4* sw4 = (float4*)s_w;
        const int n4 = NPTS * 3 / 4;  // 384
        #pragma unroll
        for (int i = t; i < n4; i += BLOCK) { ss4[i] = sb4[i]; st4[i] = tb4[i]; }
        if (t < NPTS / 4) sw4[t] = wb4[t];
    }
    __syncthreads();

    // 16 moments: [W, m_s(3), m_t(3), M(9 row-major, M_ij = sum w*src_i*tgt_j)]
    float acc[16];
    #pragma unroll
    for (int i = 0; i < 16; ++i) acc[i] = 0.f;

    #pragma unroll
    for (int k = 0; k < NPTS / BLOCK; ++k) {
        const int p = t + k * BLOCK;
        float w = s_w[p];
        w = (w < 0.f) ? 0.f : w;  // WEIGHT_THRESHOLD = 0.0
        const float sx = s_s[3 * p + 0], sy = s_s[3 * p + 1], sz = s_s[3 * p + 2];
        const float tx = s_t[3 * p + 0], ty = s_t[3 * p + 1], tz = s_t[3 * p + 2];
        acc[0] += w;
        acc[1] += w * sx; acc[2] += w * sy; acc[3] += w * sz;
        acc[4] += w * tx; acc[5] += w * ty; acc[6] += w * tz;
        const float wsx = w * sx, wsy = w * sy, wsz = w * sz;
        acc[7]  += wsx * tx; acc[8]  += wsx * ty; acc[9]  += wsx * tz;
        acc[10] += wsy * tx; acc[11] += wsy * ty; acc[12] += wsy * tz;
        acc[13] += wsz * tx; acc[14] += wsz * ty; acc[15] += wsz * tz;
    }

    // wave (64-lane) shuffle reduction
    #pragma unroll
    for (int off = 32; off > 0; off >>= 1) {
        #pragma unroll
        for (int i = 0; i < 16; ++i)
            acc[i] += __shfl_down(acc[i], off, 64);
    }

    __shared__ float red[BLOCK / 64][16];
    const int wave = t >> 6, lane = t & 63;
    if (lane == 0) {
        #pragma unroll
        for (int i = 0; i < 16; ++i) red[wave][i] = acc[i];
    }
    __syncthreads();

    if (t == 0) {
        double m[16];
        #pragma unroll
        for (int i = 0; i < 16; ++i)
            m[i] = (double)red[0][i] + (double)red[1][i]
                 + (double)red[2][i] + (double)red[3][i];

        const double T = m[0] + 1e-5;       // sum(w) + EPS
        const double f = 2.0 - m[0] / T;
        const double cs[3] = { m[1] / T, m[2] / T, m[3] / T };  // src centroid
        const double ct[3] = { m[4] / T, m[5] / T, m[6] / T };  // tgt centroid
        double H[3][3];
        for (int i = 0; i < 3; ++i)
            for (int j = 0; j < 3; ++j)
                H[i][j] = m[7 + i * 3 + j] / T - f * cs[i] * ct[j];

        // A = H^T H (symmetric PSD)
        double A[3][3];
        for (int i = 0; i < 3; ++i)
            for (int j = 0; j < 3; ++j)
                A[i][j] = H[0][i] * H[0][j] + H[1][i] * H[1][j] + H[2][i] * H[2][j];

        // Jacobi eigendecomposition: A = V diag V^T
        double V[3][3] = { {1, 0, 0}, {0, 1, 0}, {0, 0, 1} };
        for (int sweep = 0; sweep < 10; ++sweep) {
            for (int pair = 0; pair < 3; ++pair) {
                const int p = (pair == 2) ? 1 : 0;
                const int q = (pair == 0) ? 1 : 2;
                const double apq = A[p][q];
                if (fabs(apq) < 1e-40) continue;
                const double theta = (A[q][q] - A[p][p]) / (2.0 * apq);
                const double tt = ((theta >= 0.0) ? 1.0 : -1.0)
                                / (fabs(theta) + sqrt(theta * theta + 1.0));
                const double c = 1.0 / sqrt(tt * tt + 1.0);
                const double sn = tt * c;
                for (int k = 0; k < 3; ++k) {  // A <- A G
                    const double akp = A[k][p], akq = A[k][q];
                    A[k][p] = c * akp - sn * akq;
                    A[k][q] = sn * akp + c * akq;
                }
                for (int k = 0; k < 3; ++k) {  // A <- G^T A
                    const double apk = A[p][k], aqk = A[q][k];
                    A[p][k] = c * apk - sn * aqk;
                    A[q][k] = sn * apk + c * aqk;
                }
                for (int k = 0; k < 3; ++k) {  // V <- V G
                    const double vkp = V[k][p], vkq = V[k][q];
                    V[k][p] = c * vkp - sn * vkq;
                    V[k][q] = sn * vkp + c * vkq;
                }
            }
        }

        // sort eigenpairs descending
        const double lam[3] = { A[0][0], A[1][1], A[2][2] };
        int i0 = 0, i1 = 1, i2 = 2;
        if (lam[i0] < lam[i1]) { int tmp = i0; i0 = i1; i1 = tmp; }
        if (lam[i0] < lam[i2]) { int tmp = i0; i0 = i2; i2 = tmp; }
        if (lam[i1] < lam[i2]) { int tmp = i1; i1 = i2; i2 = tmp; }

        const double v1[3] = { V[0][i0], V[1][i0], V[2][i0] };
        const double v2[3] = { V[0][i1], V[1][i1], V[2][i1] };
        const double v3[3] = { v1[1] * v2[2] - v1[2] * v2[1],
                               v1[2] * v2[0] - v1[0] * v2[2],
                               v1[0] * v2[1] - v1[1] * v2[0] };

        double u1[3], u2[3], u3[3];
        for (int i = 0; i < 3; ++i)
            u1[i] = H[i][0] * v1[0] + H[i][1] * v1[1] + H[i][2] * v1[2];
        double n1 = sqrt(u1[0] * u1[0] + u1[1] * u1[1] + u1[2] * u1[2]);
        n1 = (n1 > 1e-30) ? n1 : 1e-30;
        for (int i = 0; i < 3; ++i) u1[i] /= n1;

        for (int i = 0; i < 3; ++i)
            u2[i] = H[i][0] * v2[0] + H[i][1] * v2[1] + H[i][2] * v2[2];
        const double d12 = u1[0] * u2[0] + u1[1] * u2[1] + u1[2] * u2[2];
        for (int i = 0; i < 3; ++i) u2[i] -= d12 * u1[i];
        double n2 = sqrt(u2[0] * u2[0] + u2[1] * u2[1] + u2[2] * u2[2]);
        n2 = (n2 > 1e-30) ? n2 : 1e-30;
        for (int i = 0; i < 3; ++i) u2[i] /= n2;

        u3[0] = u1[1] * u2[2] - u1[2] * u2[1];
        u3[1] = u1[2] * u2[0] - u1[0] * u2[2];
        u3[2] = u1[0] * u2[1] - u1[1] * u2[0];

        double R[3][3];
        for (int i = 0; i < 3; ++i)
            for (int j = 0; j < 3; ++j)
                R[i][j] = v1[i] * u1[j] + v2[i] * u2[j] + v3[i] * u3[j];

        double tv[3];
        for (int i = 0; i < 3; ++i)
            tv[i] = ct[i] - (R[i][0] * cs[0] + R[i][1] * cs[1] + R[i][2] * cs[2]);

        float* outR = out + (size_t)b * 9;
        for (int i = 0; i < 3; ++i)
            for (int j = 0; j < 3; ++j)
                outR[i * 3 + j] = (float)R[i][j];
        float* outT = out + (size_t)B * 9 + (size_t)b * 3;
        for (int i = 0; i < 3; ++i) outT[i] = (float)tv[i];
    }
}

extern "C" void kernel_launch(void* const* d_in, const int* in_sizes, int n_in,
                              void* d_out, int out_size, void* d_ws, size_t ws_size,
                              hipStream_t stream) {
    const float* src = (const float*)d_in[0];
    const float* tgt = (const float*)d_in[1];
    const float* wts = (const float*)d_in[2];
    float* out = (float*)d_out;
    const int B = out_size / 12;  // 9 (R) + 3 (t) floats per batch
    wproc_kernel<<<B, BLOCK, 0, stream>>>(src, tgt, wts, out, B);
}

// Round 2
// 160.258 us; speedup vs baseline: 1.1090x; 1.1090x over previous
//
#include <hip/hip_runtime.h>

#define NPTS 512
#define BLOCK 256

// ---------------------------------------------------------------------------
// Kernel 1: per-batch weighted moments.
// One block per batch: stage (src,tgt,w) to LDS with float4 loads, reduce 16
// moments [W, m_s(3), m_t(3), M(9)] via wave shuffles + LDS, write to ws.
// ---------------------------------------------------------------------------
__global__ __launch_bounds__(BLOCK) void wproc_moments(
    const float* __restrict__ src,
    const float* __restrict__ tgt,
    const float* __restrict__ wts,
    float* __restrict__ ws)
{
    const int b = blockIdx.x;
    const int t = threadIdx.x;

    __shared__ float s_s[NPTS * 3];
    __shared__ float s_t[NPTS * 3];
    __shared__ float s_w[NPTS];

    {
        const float4* sb4 = (const float4*)(src + (size_t)b * (NPTS * 3));
        const float4* tb4 = (const float4*)(tgt + (size_t)b * (NPTS * 3));
        const float4* wb4 = (const float4*)(wts + (size_t)b * NPTS);
        float4* ss4 = (float4*)s_s;
        float4* st4 = (float4*)s_t;
        float4* sw4 = (float4*)s_w;
        const int n4 = NPTS * 3 / 4;  // 384
        for (int i = t; i < n4; i += BLOCK) { ss4[i] = sb4[i]; st4[i] = tb4[i]; }
        if (t < NPTS / 4) sw4[t] = wb4[t];
    }
    __syncthreads();

    float acc[16];
    #pragma unroll
    for (int i = 0; i < 16; ++i) acc[i] = 0.f;

    #pragma unroll
    for (int k = 0; k < NPTS / BLOCK; ++k) {
        const int p = t + k * BLOCK;
        float w = s_w[p];
        w = (w < 0.f) ? 0.f : w;  // WEIGHT_THRESHOLD = 0.0
        const float sx = s_s[3 * p + 0], sy = s_s[3 * p + 1], sz = s_s[3 * p + 2];
        const float tx = s_t[3 * p + 0], ty = s_t[3 * p + 1], tz = s_t[3 * p + 2];
        acc[0] += w;
        acc[1] += w * sx; acc[2] += w * sy; acc[3] += w * sz;
        acc[4] += w * tx; acc[5] += w * ty; acc[6] += w * tz;
        const float wsx = w * sx, wsy = w * sy, wsz = w * sz;
        acc[7]  += wsx * tx; acc[8]  += wsx * ty; acc[9]  += wsx * tz;
        acc[10] += wsy * tx; acc[11] += wsy * ty; acc[12] += wsy * tz;
        acc[13] += wsz * tx; acc[14] += wsz * ty; acc[15] += wsz * tz;
    }

    // wave (64-lane) shuffle reduction
    #pragma unroll
    for (int off = 32; off > 0; off >>= 1) {
        #pragma unroll
        for (int i = 0; i < 16; ++i)
            acc[i] += __shfl_down(acc[i], off, 64);
    }

    __shared__ float red[BLOCK / 64][16];
    const int wave = t >> 6, lane = t & 63;
    if (lane == 0) {
        #pragma unroll
        for (int i = 0; i < 16; ++i) red[wave][i] = acc[i];
    }
    __syncthreads();

    if (t < 16) {
        ws[(size_t)b * 16 + t] =
            red[0][t] + red[1][t] + red[2][t] + red[3][t];
    }
}

// ---------------------------------------------------------------------------
// Kernel 2: per-batch 3x3 Procrustes solve, ONE LANE PER BATCH (fully
// parallel -- this was the serial bottleneck when it lived on thread 0 of
// the reduction block).
//
// Algebra: with T = sum(w)+eps:
//   src_c = m_s/T, tgt_c = m_t/T
//   H = M/T - (2 - W/T) * src_c * tgt_c^T   (exact expansion of centered cov)
// SVD-free rotation: Jacobi eigendecomp of A = H^T H -> V; v3 := v1 x v2,
// u_i = H v_i (Gram-Schmidt), u3 := u1 x u2; R = V U^T. The cross products
// force det(U)=det(V)=+1, reproducing the reference's diag(1,1,sign(det))
// reflection correction exactly.
// ---------------------------------------------------------------------------
__global__ __launch_bounds__(BLOCK) void wproc_solve(
    const float* __restrict__ ws,
    float* __restrict__ out,
    int B)
{
    const int b = blockIdx.x * BLOCK + threadIdx.x;
    if (b >= B) return;

    double m[16];
    #pragma unroll
    for (int i = 0; i < 16; ++i) m[i] = (double)ws[(size_t)b * 16 + i];

    const double T = m[0] + 1e-5;       // sum(w) + EPS
    const double f = 2.0 - m[0] / T;
    const double cs[3] = { m[1] / T, m[2] / T, m[3] / T };
    const double ct[3] = { m[4] / T, m[5] / T, m[6] / T };
    double H[3][3];
    for (int i = 0; i < 3; ++i)
        for (int j = 0; j < 3; ++j)
            H[i][j] = m[7 + i * 3 + j] / T - f * cs[i] * ct[j];

    // A = H^T H (symmetric PSD)
    double A[3][3];
    for (int i = 0; i < 3; ++i)
        for (int j = 0; j < 3; ++j)
            A[i][j] = H[0][i] * H[0][j] + H[1][i] * H[1][j] + H[2][i] * H[2][j];

    // Jacobi eigendecomposition: A = V diag V^T
    double V[3][3] = { {1, 0, 0}, {0, 1, 0}, {0, 0, 1} };
    for (int sweep = 0; sweep < 8; ++sweep) {
        for (int pair = 0; pair < 3; ++pair) {
            const int p = (pair == 2) ? 1 : 0;
            const int q = (pair == 0) ? 1 : 2;
            const double apq = A[p][q];
            if (fabs(apq) < 1e-40) continue;
            const double theta = (A[q][q] - A[p][p]) / (2.0 * apq);
            const double tt = ((theta >= 0.0) ? 1.0 : -1.0)
                            / (fabs(theta) + sqrt(theta * theta + 1.0));
            const double c = 1.0 / sqrt(tt * tt + 1.0);
            const double sn = tt * c;
            for (int k = 0; k < 3; ++k) {  // A <- A G
                const double akp = A[k][p], akq = A[k][q];
                A[k][p] = c * akp - sn * akq;
                A[k][q] = sn * akp + c * akq;
            }
            for (int k = 0; k < 3; ++k) {  // A <- G^T A
                const double apk = A[p][k], aqk = A[q][k];
                A[p][k] = c * apk - sn * aqk;
                A[q][k] = sn * apk + c * aqk;
            }
            for (int k = 0; k < 3; ++k) {  // V <- V G
                const double vkp = V[k][p], vkq = V[k][q];
                V[k][p] = c * vkp - sn * vkq;
                V[k][q] = sn * vkp + c * vkq;
            }
        }
    }

    // sort eigenpairs descending
    const double lam[3] = { A[0][0], A[1][1], A[2][2] };
    int i0 = 0, i1 = 1, i2 = 2;
    if (lam[i0] < lam[i1]) { int tmp = i0; i0 = i1; i1 = tmp; }
    if (lam[i0] < lam[i2]) { int tmp = i0; i0 = i2; i2 = tmp; }
    if (lam[i1] < lam[i2]) { int tmp = i1; i1 = i2; i2 = tmp; }

    const double v1[3] = { V[0][i0], V[1][i0], V[2][i0] };
    const double v2[3] = { V[0][i1], V[1][i1], V[2][i1] };
    const double v3[3] = { v1[1] * v2[2] - v1[2] * v2[1],
                           v1[2] * v2[0] - v1[0] * v2[2],
                           v1[0] * v2[1] - v1[1] * v2[0] };

    double u1[3], u2[3], u3[3];
    for (int i = 0; i < 3; ++i)
        u1[i] = H[i][0] * v1[0] + H[i][1] * v1[1] + H[i][2] * v1[2];
    double n1 = sqrt(u1[0] * u1[0] + u1[1] * u1[1] + u1[2] * u1[2]);
    n1 = (n1 > 1e-30) ? n1 : 1e-30;
    for (int i = 0; i < 3; ++i) u1[i] /= n1;

    for (int i = 0; i < 3; ++i)
        u2[i] = H[i][0] * v2[0] + H[i][1] * v2[1] + H[i][2] * v2[2];
    const double d12 = u1[0] * u2[0] + u1[1] * u2[1] + u1[2] * u2[2];
    for (int i = 0; i < 3; ++i) u2[i] -= d12 * u1[i];
    double n2 = sqrt(u2[0] * u2[0] + u2[1] * u2[1] + u2[2] * u2[2]);
    n2 = (n2 > 1e-30) ? n2 : 1e-30;
    for (int i = 0; i < 3; ++i) u2[i] /= n2;

    u3[0] = u1[1] * u2[2] - u1[2] * u2[1];
    u3[1] = u1[2] * u2[0] - u1[0] * u2[2];
    u3[2] = u1[0] * u2[1] - u1[1] * u2[0];

    double R[3][3];
    for (int i = 0; i < 3; ++i)
        for (int j = 0; j < 3; ++j)
            R[i][j] = v1[i] * u1[j] + v2[i] * u2[j] + v3[i] * u3[j];

    double tv[3];
    for (int i = 0; i < 3; ++i)
        tv[i] = ct[i] - (R[i][0] * cs[0] + R[i][1] * cs[1] + R[i][2] * cs[2]);

    float* outR = out + (size_t)b * 9;
    for (int i = 0; i < 3; ++i)
        for (int j = 0; j < 3; ++j)
            outR[i * 3 + j] = (float)R[i][j];
    float* outT = out + (size_t)B * 9 + (size_t)b * 3;
    for (int i = 0; i < 3; ++i) outT[i] = (float)tv[i];
}

extern "C" void kernel_launch(void* const* d_in, const int* in_sizes, int n_in,
                              void* d_out, int out_size, void* d_ws, size_t ws_size,
                              hipStream_t stream) {
    const float* src = (const float*)d_in[0];
    const float* tgt = (const float*)d_in[1];
    const float* wts = (const float*)d_in[2];
    float* out = (float*)d_out;
    float* ws = (float*)d_ws;   // 16 floats per batch = 512 KB
    const int B = out_size / 12;  // 9 (R) + 3 (t) floats per batch

    wproc_moments<<<B, BLOCK, 0, stream>>>(src, tgt, wts, ws);
    wproc_solve<<<(B + BLOCK - 1) / BLOCK, BLOCK, 0, stream>>>(ws, out, B);
}

// Round 3
// 149.019 us; speedup vs baseline: 1.1926x; 1.0754x over previous
//
#include <hip/hip_runtime.h>

#define NPTS 512
#define BLOCK 256
#define WAVES_PER_BLOCK 4   // one wave (64 lanes) per batch

// ---------------------------------------------------------------------------
// Kernel 1: per-batch weighted moments — ONE WAVE PER BATCH.
// Lane L owns points [8L, 8L+8): 24 consecutive floats of src/tgt = exactly
// 6 float4 loads each (no LDS staging), plus 2 float4 of w. Per-lane fp32
// accumulation of 16 moments [W, m_s(3), m_t(3), M(9)], then a
// transpose-reduce via LDS: each lane writes 16 partials into a padded
// [16][68] region (bank-conflict-free), lanes 0..15 each sum one moment's
// 64-float row with 16 ds_read_b128. This replaces the 96-op shuffle
// butterfly (ds_bpermute storm) that made R2's kernel LDS-pipe-bound.
// ---------------------------------------------------------------------------
__global__ __launch_bounds__(BLOCK) void wproc_moments(
    const float* __restrict__ src,
    const float* __restrict__ tgt,
    const float* __restrict__ wts,
    float* __restrict__ ws)
{
    const int wave = threadIdx.x >> 6;
    const int lane = threadIdx.x & 63;
    const int b = blockIdx.x * WAVES_PER_BLOCK + wave;  // grid = B/4 exact (B=8192)

    const float4* s4 = (const float4*)(src + (size_t)b * (NPTS * 3)) + 6 * lane;
    const float4* t4 = (const float4*)(tgt + (size_t)b * (NPTS * 3)) + 6 * lane;
    const float4* w4 = (const float4*)(wts + (size_t)b * NPTS) + 2 * lane;

    float4 sv[6], tv[6], wv[2];
    #pragma unroll
    for (int k = 0; k < 6; ++k) { sv[k] = s4[k]; tv[k] = t4[k]; }
    wv[0] = w4[0];
    wv[1] = w4[1];

    float sf[24], tf[24], wf[8];
    #pragma unroll
    for (int k = 0; k < 6; ++k) {
        sf[4 * k + 0] = sv[k].x; sf[4 * k + 1] = sv[k].y;
        sf[4 * k + 2] = sv[k].z; sf[4 * k + 3] = sv[k].w;
        tf[4 * k + 0] = tv[k].x; tf[4 * k + 1] = tv[k].y;
        tf[4 * k + 2] = tv[k].z; tf[4 * k + 3] = tv[k].w;
    }
    wf[0] = wv[0].x; wf[1] = wv[0].y; wf[2] = wv[0].z; wf[3] = wv[0].w;
    wf[4] = wv[1].x; wf[5] = wv[1].y; wf[6] = wv[1].z; wf[7] = wv[1].w;

    float acc[16];
    #pragma unroll
    for (int i = 0; i < 16; ++i) acc[i] = 0.f;

    #pragma unroll
    for (int j = 0; j < 8; ++j) {
        float w = wf[j];
        w = (w < 0.f) ? 0.f : w;  // WEIGHT_THRESHOLD = 0.0
        const float sx = sf[3 * j + 0], sy = sf[3 * j + 1], sz = sf[3 * j + 2];
        const float tx = tf[3 * j + 0], ty = tf[3 * j + 1], tz = tf[3 * j + 2];
        acc[0] += w;
        acc[1] += w * sx; acc[2] += w * sy; acc[3] += w * sz;
        acc[4] += w * tx; acc[5] += w * ty; acc[6] += w * tz;
        const float wsx = w * sx, wsy = w * sy, wsz = w * sz;
        acc[7]  += wsx * tx; acc[8]  += wsx * ty; acc[9]  += wsx * tz;
        acc[10] += wsy * tx; acc[11] += wsy * ty; acc[12] += wsy * tz;
        acc[13] += wsz * tx; acc[14] += wsz * ty; acc[15] += wsz * tz;
    }

    // transpose-reduce via LDS. Row stride 68 floats (=272 B, 16B-aligned,
    // and (68 mod 32)=4 staggers banks): writes are 2-way aliased (free),
    // the 16-lane b128 row reads are 2-way aliased (free).
    __shared__ float xp[WAVES_PER_BLOCK][16][68];
    #pragma unroll
    for (int m = 0; m < 16; ++m) xp[wave][m][lane] = acc[m];
    __syncthreads();

    if (lane < 16) {
        const float4* row = (const float4*)&xp[wave][lane][0];
        float4 s = row[0];
        #pragma unroll
        for (int k = 1; k < 16; ++k) {
            float4 r = row[k];
            s.x += r.x; s.y += r.y; s.z += r.z; s.w += r.w;
        }
        ws[(size_t)b * 16 + lane] = (s.x + s.y) + (s.z + s.w);
    }
}

// ---------------------------------------------------------------------------
// Kernel 2: per-batch 3x3 Procrustes solve, one lane per batch.
//
// Algebra: with T = sum(w)+eps:
//   src_c = m_s/T, tgt_c = m_t/T
//   H = M/T - (2 - W/T) * src_c * tgt_c^T   (exact expansion of centered cov)
// SVD-free rotation: Jacobi eigendecomp of A = H^T H -> V; v3 := v1 x v2,
// u_i = H v_i (Gram-Schmidt), u3 := u1 x u2; R = V U^T. The cross products
// force det(U)=det(V)=+1, reproducing the reference's diag(1,1,sign(det))
// reflection correction exactly. 5 Jacobi sweeps (quadratic convergence;
// 8 was overkill — absmax margin is 10x).
// ---------------------------------------------------------------------------
__global__ __launch_bounds__(BLOCK) void wproc_solve(
    const float* __restrict__ ws,
    float* __restrict__ out,
    int B)
{
    const int b = blockIdx.x * BLOCK + threadIdx.x;
    if (b >= B) return;

    double m[16];
    #pragma unroll
    for (int i = 0; i < 16; ++i) m[i] = (double)ws[(size_t)b * 16 + i];

    const double T = m[0] + 1e-5;       // sum(w) + EPS
    const double f = 2.0 - m[0] / T;
    const double cs[3] = { m[1] / T, m[2] / T, m[3] / T };
    const double ct[3] = { m[4] / T, m[5] / T, m[6] / T };
    double H[3][3];
    for (int i = 0; i < 3; ++i)
        for (int j = 0; j < 3; ++j)
            H[i][j] = m[7 + i * 3 + j] / T - f * cs[i] * ct[j];

    // A = H^T H (symmetric PSD)
    double A[3][3];
    for (int i = 0; i < 3; ++i)
        for (int j = 0; j < 3; ++j)
            A[i][j] = H[0][i] * H[0][j] + H[1][i] * H[1][j] + H[2][i] * H[2][j];

    // Jacobi eigendecomposition: A = V diag V^T
    double V[3][3] = { {1, 0, 0}, {0, 1, 0}, {0, 0, 1} };
    for (int sweep = 0; sweep < 5; ++sweep) {
        for (int pair = 0; pair < 3; ++pair) {
            const int p = (pair == 2) ? 1 : 0;
            const int q = (pair == 0) ? 1 : 2;
            const double apq = A[p][q];
            if (apq == 0.0) continue;
            const double theta = (A[q][q] - A[p][p]) / (2.0 * apq);
            const double tt = ((theta >= 0.0) ? 1.0 : -1.0)
                            / (fabs(theta) + sqrt(theta * theta + 1.0));
            const double c = 1.0 / sqrt(tt * tt + 1.0);
            const double sn = tt * c;
            for (int k = 0; k < 3; ++k) {  // A <- A G
                const double akp = A[k][p], akq = A[k][q];
                A[k][p] = c * akp - sn * akq;
                A[k][q] = sn * akp + c * akq;
            }
            for (int k = 0; k < 3; ++k) {  // A <- G^T A
                const double apk = A[p][k], aqk = A[q][k];
                A[p][k] = c * apk - sn * aqk;
                A[q][k] = sn * apk + c * aqk;
            }
            for (int k = 0; k < 3; ++k) {  // V <- V G
                const double vkp = V[k][p], vkq = V[k][q];
                V[k][p] = c * vkp - sn * vkq;
                V[k][q] = sn * vkp + c * vkq;
            }
        }
    }

    // sort eigenpairs descending
    const double lam[3] = { A[0][0], A[1][1], A[2][2] };
    int i0 = 0, i1 = 1, i2 = 2;
    if (lam[i0] < lam[i1]) { int tmp = i0; i0 = i1; i1 = tmp; }
    if (lam[i0] < lam[i2]) { int tmp = i0; i0 = i2; i2 = tmp; }
    if (lam[i1] < lam[i2]) { int tmp = i1; i1 = i2; i2 = tmp; }

    const double v1[3] = { V[0][i0], V[1][i0], V[2][i0] };
    const double v2[3] = { V[0][i1], V[1][i1], V[2][i1] };
    const double v3[3] = { v1[1] * v2[2] - v1[2] * v2[1],
                           v1[2] * v2[0] - v1[0] * v2[2],
                           v1[0] * v2[1] - v1[1] * v2[0] };

    double u1[3], u2[3], u3[3];
    for (int i = 0; i < 3; ++i)
        u1[i] = H[i][0] * v1[0] + H[i][1] * v1[1] + H[i][2] * v1[2];
    double n1 = sqrt(u1[0] * u1[0] + u1[1] * u1[1] + u1[2] * u1[2]);
    n1 = (n1 > 1e-30) ? n1 : 1e-30;
    for (int i = 0; i < 3; ++i) u1[i] /= n1;

    for (int i = 0; i < 3; ++i)
        u2[i] = H[i][0] * v2[0] + H[i][1] * v2[1] + H[i][2] * v2[2];
    const double d12 = u1[0] * u2[0] + u1[1] * u2[1] + u1[2] * u2[2];
    for (int i = 0; i < 3; ++i) u2[i] -= d12 * u1[i];
    double n2 = sqrt(u2[0] * u2[0] + u2[1] * u2[1] + u2[2] * u2[2]);
    n2 = (n2 > 1e-30) ? n2 : 1e-30;
    for (int i = 0; i < 3; ++i) u2[i] /= n2;

    u3[0] = u1[1] * u2[2] - u1[2] * u2[1];
    u3[1] = u1[2] * u2[0] - u1[0] * u2[2];
    u3[2] = u1[0] * u2[1] - u1[1] * u2[0];

    double R[3][3];
    for (int i = 0; i < 3; ++i)
        for (int j = 0; j < 3; ++j)
            R[i][j] = v1[i] * u1[j] + v2[i] * u2[j] + v3[i] * u3[j];

    double tv[3];
    for (int i = 0; i < 3; ++i)
        tv[i] = ct[i] - (R[i][0] * cs[0] + R[i][1] * cs[1] + R[i][2] * cs[2]);

    float* outR = out + (size_t)b * 9;
    for (int i = 0; i < 3; ++i)
        for (int j = 0; j < 3; ++j)
            outR[i * 3 + j] = (float)R[i][j];
    float* outT = out + (size_t)B * 9 + (size_t)b * 3;
    for (int i = 0; i < 3; ++i) outT[i] = (float)tv[i];
}

extern "C" void kernel_launch(void* const* d_in, const int* in_sizes, int n_in,
                              void* d_out, int out_size, void* d_ws, size_t ws_size,
                              hipStream_t stream) {
    const float* src = (const float*)d_in[0];
    const float* tgt = (const float*)d_in[1];
    const float* wts = (const float*)d_in[2];
    float* out = (float*)d_out;
    float* ws = (float*)d_ws;   // 16 floats per batch = 512 KB
    const int B = out_size / 12;  // 9 (R) + 3 (t) floats per batch; B=8192 (mult of 4)

    wproc_moments<<<B / WAVES_PER_BLOCK, BLOCK, 0, stream>>>(src, tgt, wts, ws);
    wproc_solve<<<(B + BLOCK - 1) / BLOCK, BLOCK, 0, stream>>>(ws, out, B);
}

// Round 4
// 146.349 us; speedup vs baseline: 1.2144x; 1.0182x over previous
//
#include <hip/hip_runtime.h>

#define NPTS 512
#define BLOCK 256
#define XPS 68   // xp row stride (floats): mult of 4 (16B-aligned rows), mod 32 = 4 staggers banks

// ---------------------------------------------------------------------------
// Kernel 1: per-batch weighted moments — one block (4 waves) per batch.
//
// R2 lesson: coalesced loads are mandatory (96-B-stride lane loads inflate
// L1 line transactions 6x -> 42 us). R3 lesson: shuffle butterflies are a
// DS-pipe storm (430 DS-ops/batch -> 50 us). This round: coalesced float4
// staging + cheap transpose-reduce.
//   stage:  src/tgt -> LDS via perfectly coalesced b128 (w straight from
//           global, stride-4B coalesced)
//   accum:  thread t handles points t and t+256; LDS reads at dword stride 3
//           (odd -> 2 lanes/bank = free)
//   reduce: per-wave transpose into padded xp[16][68]; lane (m + 16q) sums
//           quarter q of moment-m's row (4x ds_read_b128, uniform 8/bank =
//           inherent minimum), 2x shfl_xor to fold quarters; 4x16 cross-wave
//           combine in LDS.
// ---------------------------------------------------------------------------
__global__ __launch_bounds__(BLOCK) void wproc_moments(
    const float* __restrict__ src,
    const float* __restrict__ tgt,
    const float* __restrict__ wts,
    float* __restrict__ ws)
{
    const int b = blockIdx.x;
    const int t = threadIdx.x;
    const int wave = t >> 6, lane = t & 63;

    __shared__ float s_s[NPTS * 3];
    __shared__ float s_t[NPTS * 3];
    __shared__ float xp[4][16][XPS];
    __shared__ float red[4][16];

    // ---- coalesced stage (384 float4 per array = 256 + 128) ----
    {
        const float4* sb4 = (const float4*)(src + (size_t)b * (NPTS * 3));
        const float4* tb4 = (const float4*)(tgt + (size_t)b * (NPTS * 3));
        float4* ss4 = (float4*)s_s;
        float4* st4 = (float4*)s_t;
        ss4[t] = sb4[t];
        st4[t] = tb4[t];
        if (t < 128) { ss4[256 + t] = sb4[256 + t]; st4[256 + t] = tb4[256 + t]; }
    }
    // w direct from global (coalesced b32)
    const float* wb = wts + (size_t)b * NPTS;
    float wA = wb[t];
    float wB = wb[t + 256];
    __syncthreads();

    // ---- accumulate 16 moments over 2 points ----
    // [W, m_s(3), m_t(3), M(9) row-major M_ij = sum w*src_i*tgt_j]
    float acc[16];
    #pragma unroll
    for (int i = 0; i < 16; ++i) acc[i] = 0.f;

    #pragma unroll
    for (int k = 0; k < 2; ++k) {
        const int p = t + k * 256;
        float w = k ? wB : wA;
        w = (w < 0.f) ? 0.f : w;  // WEIGHT_THRESHOLD = 0.0
        const float sx = s_s[3 * p + 0], sy = s_s[3 * p + 1], sz = s_s[3 * p + 2];
        const float tx = s_t[3 * p + 0], ty = s_t[3 * p + 1], tz = s_t[3 * p + 2];
        acc[0] += w;
        acc[1] += w * sx; acc[2] += w * sy; acc[3] += w * sz;
        acc[4] += w * tx; acc[5] += w * ty; acc[6] += w * tz;
        const float wsx = w * sx, wsy = w * sy, wsz = w * sz;
        acc[7]  += wsx * tx; acc[8]  += wsx * ty; acc[9]  += wsx * tz;
        acc[10] += wsy * tx; acc[11] += wsy * ty; acc[12] += wsy * tz;
        acc[13] += wsz * tx; acc[14] += wsz * ty; acc[15] += wsz * tz;
    }

    // ---- per-wave transpose ----
    #pragma unroll
    for (int m = 0; m < 16; ++m) xp[wave][m][lane] = acc[m];
    __syncthreads();

    // ---- per-wave row reduce: lane = m + 16q sums quarter q of row m ----
    {
        const int m = lane & 15, q = lane >> 4;
        const float4* row = (const float4*)&xp[wave][m][0] + 4 * q;
        float4 a0 = row[0], a1 = row[1], a2 = row[2], a3 = row[3];
        a0.x += a1.x; a0.y += a1.y; a0.z += a1.z; a0.w += a1.w;
        a2.x += a3.x; a2.y += a3.y; a2.z += a3.z; a2.w += a3.w;
        a0.x += a2.x; a0.y += a2.y; a0.z += a2.z; a0.w += a2.w;
        float v = (a0.x + a0.y) + (a0.z + a0.w);
        v += __shfl_xor(v, 16, 64);
        v += __shfl_xor(v, 32, 64);
        if (q == 0) red[wave][m] = v;
    }
    __syncthreads();

    // ---- cross-wave combine + store ----
    if (t < 16) {
        ws[(size_t)b * 16 + t] =
            (red[0][t] + red[1][t]) + (red[2][t] + red[3][t]);
    }
}

// ---------------------------------------------------------------------------
// Kernel 2: per-batch 3x3 Procrustes solve, one lane per batch (~1.5 us for
// all 8192 — verified in R1/R2 arithmetic; leave untouched).
//
// Algebra: with T = sum(w)+eps:
//   src_c = m_s/T, tgt_c = m_t/T
//   H = M/T - (2 - W/T) * src_c * tgt_c^T   (exact expansion of centered cov)
// SVD-free rotation: Jacobi eigendecomp of A = H^T H -> V; v3 := v1 x v2,
// u_i = H v_i (Gram-Schmidt), u3 := u1 x u2; R = V U^T. The cross products
// force det(U)=det(V)=+1, reproducing the reference's diag(1,1,sign(det))
// reflection correction exactly.
// ---------------------------------------------------------------------------
__global__ __launch_bounds__(BLOCK) void wproc_solve(
    const float* __restrict__ ws,
    float* __restrict__ out,
    int B)
{
    const int b = blockIdx.x * BLOCK + threadIdx.x;
    if (b >= B) return;

    double m[16];
    #pragma unroll
    for (int i = 0; i < 16; ++i) m[i] = (double)ws[(size_t)b * 16 + i];

    const double T = m[0] + 1e-5;       // sum(w) + EPS
    const double f = 2.0 - m[0] / T;
    const double cs[3] = { m[1] / T, m[2] / T, m[3] / T };
    const double ct[3] = { m[4] / T, m[5] / T, m[6] / T };
    double H[3][3];
    for (int i = 0; i < 3; ++i)
        for (int j = 0; j < 3; ++j)
            H[i][j] = m[7 + i * 3 + j] / T - f * cs[i] * ct[j];

    // A = H^T H (symmetric PSD)
    double A[3][3];
    for (int i = 0; i < 3; ++i)
        for (int j = 0; j < 3; ++j)
            A[i][j] = H[0][i] * H[0][j] + H[1][i] * H[1][j] + H[2][i] * H[2][j];

    // Jacobi eigendecomposition: A = V diag V^T
    double V[3][3] = { {1, 0, 0}, {0, 1, 0}, {0, 0, 1} };
    for (int sweep = 0; sweep < 5; ++sweep) {
        for (int pair = 0; pair < 3; ++pair) {
            const int p = (pair == 2) ? 1 : 0;
            const int q = (pair == 0) ? 1 : 2;
            const double apq = A[p][q];
            if (apq == 0.0) continue;
            const double theta = (A[q][q] - A[p][p]) / (2.0 * apq);
            const double tt = ((theta >= 0.0) ? 1.0 : -1.0)
                            / (fabs(theta) + sqrt(theta * theta + 1.0));
            const double c = 1.0 / sqrt(tt * tt + 1.0);
            const double sn = tt * c;
            for (int k = 0; k < 3; ++k) {  // A <- A G
                const double akp = A[k][p], akq = A[k][q];
                A[k][p] = c * akp - sn * akq;
                A[k][q] = sn * akp + c * akq;
            }
            for (int k = 0; k < 3; ++k) {  // A <- G^T A
                const double apk = A[p][k], aqk = A[q][k];
                A[p][k] = c * apk - sn * aqk;
                A[q][k] = sn * apk + c * aqk;
            }
            for (int k = 0; k < 3; ++k) {  // V <- V G
                const double vkp = V[k][p], vkq = V[k][q];
                V[k][p] = c * vkp - sn * vkq;
                V[k][q] = sn * vkp + c * vkq;
            }
        }
    }

    // sort eigenpairs descending
    const double lam[3] = { A[0][0], A[1][1], A[2][2] };
    int i0 = 0, i1 = 1, i2 = 2;
    if (lam[i0] < lam[i1]) { int tmp = i0; i0 = i1; i1 = tmp; }
    if (lam[i0] < lam[i2]) { int tmp = i0; i0 = i2; i2 = tmp; }
    if (lam[i1] < lam[i2]) { int tmp = i1; i1 = i2; i2 = tmp; }

    const double v1[3] = { V[0][i0], V[1][i0], V[2][i0] };
    const double v2[3] = { V[0][i1], V[1][i1], V[2][i1] };
    const double v3[3] = { v1[1] * v2[2] - v1[2] * v2[1],
                           v1[2] * v2[0] - v1[0] * v2[2],
                           v1[0] * v2[1] - v1[1] * v2[0] };

    double u1[3], u2[3], u3[3];
    for (int i = 0; i < 3; ++i)
        u1[i] = H[i][0] * v1[0] + H[i][1] * v1[1] + H[i][2] * v1[2];
    double n1 = sqrt(u1[0] * u1[0] + u1[1] * u1[1] + u1[2] * u1[2]);
    n1 = (n1 > 1e-30) ? n1 : 1e-30;
    for (int i = 0; i < 3; ++i) u1[i] /= n1;

    for (int i = 0; i < 3; ++i)
        u2[i] = H[i][0] * v2[0] + H[i][1] * v2[1] + H[i][2] * v2[2];
    const double d12 = u1[0] * u2[0] + u1[1] * u2[1] + u1[2] * u2[2];
    for (int i = 0; i < 3; ++i) u2[i] -= d12 * u1[i];
    double n2 = sqrt(u2[0] * u2[0] + u2[1] * u2[1] + u2[2] * u2[2]);
    n2 = (n2 > 1e-30) ? n2 : 1e-30;
    for (int i = 0; i < 3; ++i) u2[i] /= n2;

    u3[0] = u1[1] * u2[2] - u1[2] * u2[1];
    u3[1] = u1[2] * u2[0] - u1[0] * u2[2];
    u3[2] = u1[0] * u2[1] - u1[1] * u2[0];

    double R[3][3];
    for (int i = 0; i < 3; ++i)
        for (int j = 0; j < 3; ++j)
            R[i][j] = v1[i] * u1[j] + v2[i] * u2[j] + v3[i] * u3[j];

    double tv[3];
    for (int i = 0; i < 3; ++i)
        tv[i] = ct[i] - (R[i][0] * cs[0] + R[i][1] * cs[1] + R[i][2] * cs[2]);

    float* outR = out + (size_t)b * 9;
    for (int i = 0; i < 3; ++i)
        for (int j = 0; j < 3; ++j)
            outR[i * 3 + j] = (float)R[i][j];
    float* outT = out + (size_t)B * 9 + (size_t)b * 3;
    for (int i = 0; i < 3; ++i) outT[i] = (float)tv[i];
}

extern "C" void kernel_launch(void* const* d_in, const int* in_sizes, int n_in,
                              void* d_out, int out_size, void* d_ws, size_t ws_size,
                              hipStream_t stream) {
    const float* src = (const float*)d_in[0];
    const float* tgt = (const float*)d_in[1];
    const float* wts = (const float*)d_in[2];
    float* out = (float*)d_out;
    float* ws = (float*)d_ws;   // 16 floats per batch = 512 KB
    const int B = out_size / 12;  // 9 (R) + 3 (t) floats per batch

    wproc_moments<<<B, BLOCK, 0, stream>>>(src, tgt, wts, ws);
    wproc_solve<<<(B + BLOCK - 1) / BLOCK, BLOCK, 0, stream>>>(ws, out, B);
}